// Round 18
// baseline (77.964 us; speedup 1.0000x reference)
//
#include <hip/hip_runtime.h>
#include <math.h>

#define H 56
#define W 56
#define B 8
#define CIN 128
#define COUT 128
#define OCH 54        // 3*DG*K*K
#define HW (H*W)      // 3136
#define JTOT 1152     // CIN*9

typedef __attribute__((ext_vector_type(8))) short bf16x8;
typedef __attribute__((ext_vector_type(4))) float f32x4;

__device__ inline ushort f2bf(float f) {
    union { float f; unsigned u; } x; x.f = f;
    unsigned r = x.u + 0x7FFFu + ((x.u >> 16) & 1u);
    return (ushort)(r >> 16);
}
__device__ inline float bf2f(ushort u) {
    union { unsigned u; float f; } x; x.u = ((unsigned)u) << 16;
    return x.f;
}

// ---------------- K0: merged relu-transpose + weight packs (R17 verbatim) ----------------
__global__ __launch_bounds__(256) void k_pre(const float* __restrict__ x,
        ushort* __restrict__ xbf, const float* __restrict__ w, ushort* __restrict__ wb,
        const float* __restrict__ wof, ushort* __restrict__ wofb) {
    __shared__ float s[64][65];
    int t = threadIdx.x;
    int bi = blockIdx.x;                    // 784 + 864
    if (bi < 784) {
        int hwb = bi % 49, cb = (bi / 49) & 1, b = bi / 98;
        int hw0 = hwb * 64, c0 = cb * 64;
        const float* src = x + (size_t)(b * CIN + c0) * HW + hw0;
        #pragma unroll
        for (int k = 0; k < 16; ++k) {
            int cl = (t >> 6) + k * 4, hl = t & 63;
            s[cl][hl] = src[cl * HW + hl];
        }
        __syncthreads();
        #pragma unroll
        for (int k = 0; k < 16; ++k) {
            int hl = (t >> 6) + k * 4, cl = t & 63;
            float v = fmaxf(s[cl][hl], 0.f);
            xbf[(size_t)(b * HW + hw0 + hl) * CIN + c0 + cl] = f2bf(v);
        }
    } else {
        int bid = bi - 784;
        if (bid < 576) {
            int idx = bid * 256 + t;                 // 147456
            int o = idx / JTOT, k = idx % JTOT;
            int chunk = k >> 6, cc = k & 63;
            int g = chunk / 9, p = chunk % 9;
            int kc32l = (k >> 5) & 1, lg = (k >> 3) & 3, i3 = k & 7;
            float v = w[(size_t)o * JTOT + (g * 64 + cc) * 9 + p];
            int gran = ((chunk * 2 + kc32l) * 128 + o) * 4 + lg;
            wb[(size_t)gran * 8 + i3] = f2bf(v);
        } else {
            int i = (bid - 576) * 256 + t;           // 73728
            int j = i & 7, oc = (i >> 3) & 63, kc = i >> 9;
            int tap = kc >> 4, c = ((kc & 15) << 3) | j;
            float v = (oc < OCH) ? wof[(oc * CIN + c) * 9 + tap] : 0.f;
            wofb[i] = f2bf(v);
        }
    }
}

// ---------------- K1: 3x3 offset conv via MFMA, quarter-row blocks ----------------
// block = (b, y, xq): 14 pixels x 54(->64) oc. Patch 3 rows x 16 cols x 128 ch = 12288 B.
// Same tap/cb accumulation order as proven k_offc2; wave wv owns oc quarter wv*16..+15.
__global__ __launch_bounds__(256) void k_offc3(
    const ushort* __restrict__ xbf, const ushort* __restrict__ wofb,
    const float* __restrict__ bof, float* __restrict__ om)
{
    __shared__ uint4 s_patch[48 * 16];   // 12288 B
    int t = threadIdx.x;
    int bi = blockIdx.x;                      // 1792
    int lgid = (bi & 7) * 224 + (bi >> 3);    // XCD-chunked swizzle (1792 % 8 == 0)
    int xq = lgid & 3, y = (lgid >> 2) % H, b = (lgid >> 2) / H;

    for (int idx = t; idx < 768; idx += 256) {
        int r = idx >> 4, ck = idx & 15;
        int di = r >> 4, col = r & 15;
        int xx = xq * 14 + col - 1, yy = y + di - 1;
        uint4 v = make_uint4(0u, 0u, 0u, 0u);
        if (yy >= 0 && yy < H && xx >= 0 && xx < W)
            v = *reinterpret_cast<const uint4*>(xbf + ((size_t)((b * H + yy) * W + xx)) * CIN + ck * 8);
        s_patch[r * 16 + (ck ^ (r & 7))] = v;
    }
    __syncthreads();

    int wv = t >> 6, lane = t & 63, l15 = lane & 15, lg = lane >> 4;
    // wave wv: all 14(16) pixels x oc quarter wv*16..+15

    f32x4 acc = {0.f, 0.f, 0.f, 0.f};
    const bf16x8* wp = reinterpret_cast<const bf16x8*>(wofb);

    #pragma unroll
    for (int tap = 0; tap < 9; ++tap) {
        int di = tap / 3, dj = tap % 3;
        int col = l15 + dj; col = min(col, 15);   // padded pixels 14,15 clamped (discarded)
        int r = di * 16 + col;
        #pragma unroll
        for (int cb = 0; cb < 4; ++cb) {
            int c8 = cb * 4 + lg;
            bf16x8 af = *reinterpret_cast<const bf16x8*>(&s_patch[r * 16 + (c8 ^ (r & 7))]);
            int kc = tap * 16 + c8;
            acc = __builtin_amdgcn_mfma_f32_16x16x32_bf16(af, wp[kc * 64 + wv * 16 + l15], acc, 0, 0, 0);
        }
    }

    int p0 = lg * 4;
    int oc = wv * 16 + l15;
    int base = (b * H + y) * W + xq * 14;
    if (oc < OCH) {
        float bo = bof[oc];
        #pragma unroll
        for (int ri = 0; ri < 4; ++ri) {
            int p = p0 + ri;
            if (p < 14) om[(size_t)(base + p) * OCH + oc] = acc[ri] + bo;
        }
    }
}

// ---------------- K2: deformable gather + einsum via MFMA (R17/R8 VERBATIM) ----------------
// block = (b, h, half): 32 pixels x 128 oc, K = 18 chunks of 64
#define MLDS_IX 9216         // int[576]
#define MLDS_A  13824        // bf16 [32][64] swizzled = 4096 B
#define MLDS_B  17920        // bf16 chunk B  = 16384 B
#define MLDS_TOT 34304

__global__ __launch_bounds__(256, 4) void k_main2(
    const ushort* __restrict__ xbf, const float* __restrict__ om,
    const ushort* __restrict__ wb, const float* __restrict__ bias,
    float* __restrict__ out)
{
    __shared__ __align__(16) char smem[MLDS_TOT];
    float4* s_w4 = (float4*)smem;
    int*    s_ix = (int*)(smem + MLDS_IX);
    char*   sA   = smem + MLDS_A;
    uint4*  sBq  = (uint4*)(smem + MLDS_B);

    int t = threadIdx.x;
    int bi = blockIdx.x;                         // 896
    int lgid = (bi & 7) * 112 + (bi >> 3);       // XCD-chunked swizzle
    int half = lgid & 1;
    int rowid = lgid >> 1;
    int h = rowid % H, b = rowid / H;
    int w0 = half * 32;

    // ---- phase A: offsets / mask / packed corners ----
    for (int ent = t; ent < 32 * 18; ent += 256) {
        int pixl = ent / 18, e = ent % 18;
        int x = w0 + pixl;
        float4 w4 = {0.f, 0.f, 0.f, 0.f};
        int ip = 0;
        if (x < W) {
            const float* omp = om + ((size_t)(b * H + h) * W + x) * OCH;
            float offy = omp[e];
            float offx = omp[18 + e];
            float m = 1.f / (1.f + expf(-omp[36 + e]));
            int p = e % 9;
            float ys = offy + (float)(h - 1 + p / 3);
            float xs = offx + (float)(x - 1 + p % 3);
            float y0f = floorf(ys), x0f = floorf(xs);
            float wy = ys - y0f, wx = xs - x0f;
            int y0 = (int)y0f, x0 = (int)x0f;
            bool vy0 = (y0 >= 0) && (y0 < H), vy1 = (y0 + 1 >= 0) && (y0 + 1 < H);
            bool vx0 = (x0 >= 0) && (x0 < W), vx1 = (x0 + 1 >= 0) && (x0 + 1 < W);
            int yc0 = min(max(y0, 0), H - 1), yc1 = min(max(y0 + 1, 0), H - 1);
            int xc0 = min(max(x0, 0), W - 1), xc1 = min(max(x0 + 1, 0), W - 1);
            w4.x = (vy0 && vx0) ? (1.f - wy) * (1.f - wx) * m : 0.f;
            w4.y = (vy0 && vx1) ? (1.f - wy) * wx * m : 0.f;
            w4.z = (vy1 && vx0) ? wy * (1.f - wx) * m : 0.f;
            w4.w = (vy1 && vx1) ? wy * wx * m : 0.f;
            ip = (yc0 * W + xc0) | ((xc1 - xc0) << 12) | ((yc1 - yc0) << 13);
        }
        s_w4[ent] = w4;
        s_ix[ent] = ip;
    }

    int wave = t >> 6, l = t & 63;
    int l15 = l & 15, lg = l >> 4;
    int pt = wave >> 1, wo = wave & 1;           // pixel-tile, oc-half
    int cs = t & 15, pxb = t >> 4;               // gather: channel-slot / pix-base

    f32x4 acc[4];
    #pragma unroll
    for (int n = 0; n < 4; ++n) acc[n] = (f32x4){0.f, 0.f, 0.f, 0.f};

    const size_t xbase = (size_t)b * HW * CIN;

    for (int chunk = 0; chunk < 18; ++chunk) {
        __syncthreads();
        // stage B chunk (16KB) to LDS
        {
            const uint4* gsrc = (const uint4*)wb + (size_t)chunk * 1024;
            #pragma unroll
            for (int it = 0; it < 4; ++it)
                sBq[it * 256 + t] = gsrc[it * 256 + t];
        }
        // gather A chunk: 32 pix x 64 ch (of group g = chunk/9)
        {
            const ushort* xg = xbf + xbase + ((chunk < 9) ? 0 : 64) + cs * 4;
            #pragma unroll
            for (int it = 0; it < 2; ++it) {
                int pixl = pxb + it * 16;
                int ent = pixl * 18 + chunk;
                int ip = s_ix[ent];
                float4 w4 = s_w4[ent];
                int i00 = ip & 0xFFF;
                int dx = (ip >> 12) & 1, dy = (ip >> 13) & 1;
                const ushort* p00 = xg + (size_t)i00 * CIN;
                const ushort* p01 = p00 + dx * CIN;
                const ushort* p10 = p00 + dy * (W * CIN);
                const ushort* p11 = p10 + dx * CIN;
                ushort4 a00 = *(const ushort4*)p00;
                ushort4 a01 = *(const ushort4*)p01;
                ushort4 a10 = *(const ushort4*)p10;
                ushort4 a11 = *(const ushort4*)p11;
                float r0 = w4.x * bf2f(a00.x) + w4.y * bf2f(a01.x) + w4.z * bf2f(a10.x) + w4.w * bf2f(a11.x);
                float r1 = w4.x * bf2f(a00.y) + w4.y * bf2f(a01.y) + w4.z * bf2f(a10.y) + w4.w * bf2f(a11.y);
                float r2 = w4.x * bf2f(a00.z) + w4.y * bf2f(a01.z) + w4.z * bf2f(a10.z) + w4.w * bf2f(a11.z);
                float r3 = w4.x * bf2f(a00.w) + w4.y * bf2f(a01.w) + w4.z * bf2f(a10.w) + w4.w * bf2f(a11.w);
                ushort4 o4;
                o4.x = f2bf(r0); o4.y = f2bf(r1); o4.z = f2bf(r2); o4.w = f2bf(r3);
                // swizzled A write: granule u = cs>>1, u' = u ^ (pixl&7)
                *(ushort4*)(sA + pixl * 128 + (((cs >> 1)) ^ (pixl & 7)) * 16 + (cs & 1) * 8) = o4;
            }
        }
        __syncthreads();
        // MFMA: wave (pt, wo): 16 pix x 64 oc
        {
            int pixr = pt * 16 + l15;
            #pragma unroll
            for (int kh = 0; kh < 2; ++kh) {
                bf16x8 af = *(const bf16x8*)(sA + pixr * 128 + ((kh * 4 + lg) ^ (pixr & 7)) * 16);
                #pragma unroll
                for (int n = 0; n < 4; ++n) {
                    bf16x8 bfr = *(const bf16x8*)(sBq + kh * 512 + (wo * 64 + n * 16 + l15) * 4 + lg);
                    acc[n] = __builtin_amdgcn_mfma_f32_16x16x32_bf16(af, bfr, acc[n], 0, 0, 0);
                }
            }
        }
    }

    // ---- epilogue: direct NCHW float4 stores ----
    int pix0 = pt * 16 + lg * 4;
    if (w0 + pix0 < W) {
        #pragma unroll
        for (int n = 0; n < 4; ++n) {
            int o = wo * 64 + n * 16 + l15;
            float bo = bias[o];
            float4 st = {acc[n][0] + bo, acc[n][1] + bo, acc[n][2] + bo, acc[n][3] + bo};
            *(float4*)(out + ((size_t)(b * COUT + o) * H + h) * W + w0 + pix0) = st;
        }
    }
}

// ---------------- K3: per-channel BN partials, full-chip (R17 verbatim) ----------------
__global__ void k_stats1(const float* __restrict__ out, float* __restrict__ partials) {
    int bid = blockIdx.x;            // 256 = o*2 + bh
    int o = bid >> 1, bh = bid & 1;
    int t = threadIdx.x;
    const float4* op = reinterpret_cast<const float4*>(out);
    float s = 0.f, q = 0.f;
    for (int i = t; i < 4 * 784; i += 256) {
        int b = bh * 4 + i / 784, hw4 = i % 784;
        float4 v = op[(size_t)(b * COUT + o) * 784 + hw4];
        s += v.x + v.y + v.z + v.w;
        q += v.x * v.x + v.y * v.y + v.z * v.z + v.w * v.w;
    }
    __shared__ float ls[256], lq[256];
    ls[t] = s; lq[t] = q;
    __syncthreads();
    for (int st = 128; st > 0; st >>= 1) {
        if (t < st) { ls[t] += ls[t + st]; lq[t] += lq[t + st]; }
        __syncthreads();
    }
    if (t == 0) {
        partials[bid * 2]     = ls[0];
        partials[bid * 2 + 1] = lq[0];
    }
}

// ---------------- K4: BN apply (R17 verbatim) ----------------
__global__ void k_bn4(float* __restrict__ out, const float* __restrict__ partials,
                      const float* __restrict__ gamma, const float* __restrict__ beta) {
    int i = blockIdx.x * 256 + threadIdx.x;       // 802816 float4s
    int o = (i / 784) & 127;
    float s = partials[o * 4]     + partials[o * 4 + 2];
    float q = partials[o * 4 + 1] + partials[o * 4 + 3];
    const float invN = 1.f / 25088.f;
    float mean = s * invN;
    float rs = rsqrtf(q * invN - mean * mean + 1e-5f);
    float g = gamma[o] * rs;
    float bb = beta[o] - mean * g;
    float4 v = reinterpret_cast<float4*>(out)[i];
    v.x = v.x * g + bb; v.y = v.y * g + bb; v.z = v.z * g + bb; v.w = v.w * g + bb;
    reinterpret_cast<float4*>(out)[i] = v;
}

extern "C" void kernel_launch(void* const* d_in, const int* in_sizes, int n_in,
                              void* d_out, int out_size, void* d_ws, size_t ws_size,
                              hipStream_t stream) {
    const float* x     = (const float*)d_in[0];
    const float* wof   = (const float*)d_in[1];
    const float* bof   = (const float*)d_in[2];
    const float* w     = (const float*)d_in[3];
    const float* bias  = (const float*)d_in[4];
    const float* gamma = (const float*)d_in[5];
    const float* beta  = (const float*)d_in[6];
    float* out = (float*)d_out;
    float* ws  = (float*)d_ws;

    // ws layout identical to R17 (proven); partials aliases om_t head (dead there)
    float*  om_t  = ws;                           // 1354752 floats
    float*  partials = om_t;                      // 512 floats, used post-k_main2
    ushort* xbf   = (ushort*)(ws + 1355008);      // 3211264 ushorts
    ushort* wb    = xbf + 3211264;                // 147456 ushorts
    ushort* wofb  = wb + 147456;                  // 73728 ushorts

    hipLaunchKernelGGL(k_pre,     dim3(1648), dim3(256), 0, stream, x, xbf, w, wb, wof, wofb);
    hipLaunchKernelGGL(k_offc3,   dim3(1792), dim3(256), 0, stream, xbf, wofb, bof, om_t);
    hipLaunchKernelGGL(k_main2,   dim3(896),  dim3(256), 0, stream, xbf, om_t, wb, bias, out);
    hipLaunchKernelGGL(k_stats1,  dim3(256),  dim3(256), 0, stream, out, partials);
    hipLaunchKernelGGL(k_bn4,     dim3(3136), dim3(256), 0, stream, out, partials, gamma, beta);
}

// Round 20
// 77.614 us; speedup vs baseline: 1.0045x; 1.0045x over previous
//
#include <hip/hip_runtime.h>
#include <math.h>

#define H 56
#define W 56
#define B 8
#define CIN 128
#define COUT 128
#define OCH 54        // 3*DG*K*K
#define HW (H*W)      // 3136
#define JTOT 1152     // CIN*9

typedef __attribute__((ext_vector_type(8))) short bf16x8;
typedef __attribute__((ext_vector_type(4))) float f32x4;

__device__ inline ushort f2bf(float f) {
    union { float f; unsigned u; } x; x.f = f;
    unsigned r = x.u + 0x7FFFu + ((x.u >> 16) & 1u);
    return (ushort)(r >> 16);
}
__device__ inline float bf2f(ushort u) {
    union { unsigned u; float f; } x; x.u = ((unsigned)u) << 16;
    return x.f;
}

// ---------------- K0: merged relu-transpose + weight packs (R17 verbatim) ----------------
__global__ __launch_bounds__(256) void k_pre(const float* __restrict__ x,
        ushort* __restrict__ xbf, const float* __restrict__ w, ushort* __restrict__ wb,
        const float* __restrict__ wof, ushort* __restrict__ wofb) {
    __shared__ float s[64][65];
    int t = threadIdx.x;
    int bi = blockIdx.x;                    // 784 + 864
    if (bi < 784) {
        int hwb = bi % 49, cb = (bi / 49) & 1, b = bi / 98;
        int hw0 = hwb * 64, c0 = cb * 64;
        const float* src = x + (size_t)(b * CIN + c0) * HW + hw0;
        #pragma unroll
        for (int k = 0; k < 16; ++k) {
            int cl = (t >> 6) + k * 4, hl = t & 63;
            s[cl][hl] = src[cl * HW + hl];
        }
        __syncthreads();
        #pragma unroll
        for (int k = 0; k < 16; ++k) {
            int hl = (t >> 6) + k * 4, cl = t & 63;
            float v = fmaxf(s[cl][hl], 0.f);
            xbf[(size_t)(b * HW + hw0 + hl) * CIN + c0 + cl] = f2bf(v);
        }
    } else {
        int bid = bi - 784;
        if (bid < 576) {
            int idx = bid * 256 + t;                 // 147456
            int o = idx / JTOT, k = idx % JTOT;
            int chunk = k >> 6, cc = k & 63;
            int g = chunk / 9, p = chunk % 9;
            int kc32l = (k >> 5) & 1, lg = (k >> 3) & 3, i3 = k & 7;
            float v = w[(size_t)o * JTOT + (g * 64 + cc) * 9 + p];
            int gran = ((chunk * 2 + kc32l) * 128 + o) * 4 + lg;
            wb[(size_t)gran * 8 + i3] = f2bf(v);
        } else {
            int i = (bid - 576) * 256 + t;           // 73728
            int j = i & 7, oc = (i >> 3) & 63, kc = i >> 9;
            int tap = kc >> 4, c = ((kc & 15) << 3) | j;
            float v = (oc < OCH) ? wof[(oc * CIN + c) * 9 + tap] : 0.f;
            wofb[i] = f2bf(v);
        }
    }
}

// ---------------- K1: 3x3 offset conv via MFMA, half-row blocks (R17 verbatim) ----------------
__global__ __launch_bounds__(256) void k_offc2(
    const ushort* __restrict__ xbf, const ushort* __restrict__ wofb,
    const float* __restrict__ bof, float* __restrict__ om)
{
    __shared__ uint4 s_patch[90 * 16];   // 23040 B
    int t = threadIdx.x;
    int bi = blockIdx.x;                      // 896
    int lgid = (bi & 7) * 112 + (bi >> 3);    // XCD-chunked swizzle
    int xh = lgid & 1, y = (lgid >> 1) % H, b = (lgid >> 1) / H;

    for (int idx = t; idx < 1440; idx += 256) {
        int r = idx >> 4, ck = idx & 15;
        int di = r / 30, rr = r - di * 30;
        int xx = xh * 28 + rr - 1, yy = y + di - 1;
        uint4 v = make_uint4(0u, 0u, 0u, 0u);
        if (yy >= 0 && yy < H && xx >= 0 && xx < W)
            v = *reinterpret_cast<const uint4*>(xbf + ((size_t)((b * H + yy) * W + xx)) * CIN + ck * 8);
        s_patch[r * 16 + (ck ^ (r & 7))] = v;
    }
    __syncthreads();

    int wv = t >> 6, lane = t & 63, l15 = lane & 15, lg = lane >> 4;
    int pt = wv >> 1, wo = wv & 1;
    int ploc = pt * 16 + l15;                 // pixel (valid < 28)

    f32x4 acc0 = {0.f, 0.f, 0.f, 0.f}, acc1 = acc0;
    const bf16x8* wp = reinterpret_cast<const bf16x8*>(wofb);

    #pragma unroll
    for (int tap = 0; tap < 9; ++tap) {
        int di = tap / 3, dj = tap % 3;
        int col = ploc + dj; col = min(col, 29);
        int r = di * 30 + col;
        #pragma unroll
        for (int cb = 0; cb < 4; ++cb) {
            int c8 = cb * 4 + lg;
            bf16x8 af = *reinterpret_cast<const bf16x8*>(&s_patch[r * 16 + (c8 ^ (r & 7))]);
            int kc = tap * 16 + c8;
            acc0 = __builtin_amdgcn_mfma_f32_16x16x32_bf16(af, wp[kc * 64 + wo * 32 + l15], acc0, 0, 0, 0);
            acc1 = __builtin_amdgcn_mfma_f32_16x16x32_bf16(af, wp[kc * 64 + wo * 32 + 16 + l15], acc1, 0, 0, 0);
        }
    }

    int p0 = pt * 16 + lg * 4;
    int base = (b * H + y) * W + xh * 28;
    #pragma unroll
    for (int n = 0; n < 2; ++n) {
        int oc = wo * 32 + n * 16 + l15;
        if (oc < OCH) {
            float bo = bof[oc];
            f32x4 a = n ? acc1 : acc0;
            #pragma unroll
            for (int ri = 0; ri < 4; ++ri) {
                int p = p0 + ri;
                if (p < 28) om[(size_t)(base + p) * OCH + oc] = a[ri] + bo;
            }
        }
    }
}

// ---------------- K2: deformable gather + einsum via MFMA (R17/R8 VERBATIM) ----------------
// block = (b, h, half): 32 pixels x 128 oc, K = 18 chunks of 64
#define MLDS_IX 9216         // int[576]
#define MLDS_A  13824        // bf16 [32][64] swizzled = 4096 B
#define MLDS_B  17920        // bf16 chunk B  = 16384 B
#define MLDS_TOT 34304

__global__ __launch_bounds__(256, 4) void k_main2(
    const ushort* __restrict__ xbf, const float* __restrict__ om,
    const ushort* __restrict__ wb, const float* __restrict__ bias,
    float* __restrict__ out)
{
    __shared__ __align__(16) char smem[MLDS_TOT];
    float4* s_w4 = (float4*)smem;
    int*    s_ix = (int*)(smem + MLDS_IX);
    char*   sA   = smem + MLDS_A;
    uint4*  sBq  = (uint4*)(smem + MLDS_B);

    int t = threadIdx.x;
    int bi = blockIdx.x;                         // 896
    int lgid = (bi & 7) * 112 + (bi >> 3);       // XCD-chunked swizzle
    int half = lgid & 1;
    int rowid = lgid >> 1;
    int h = rowid % H, b = rowid / H;
    int w0 = half * 32;

    // ---- phase A: offsets / mask / packed corners ----
    for (int ent = t; ent < 32 * 18; ent += 256) {
        int pixl = ent / 18, e = ent % 18;
        int x = w0 + pixl;
        float4 w4 = {0.f, 0.f, 0.f, 0.f};
        int ip = 0;
        if (x < W) {
            const float* omp = om + ((size_t)(b * H + h) * W + x) * OCH;
            float offy = omp[e];
            float offx = omp[18 + e];
            float m = 1.f / (1.f + expf(-omp[36 + e]));
            int p = e % 9;
            float ys = offy + (float)(h - 1 + p / 3);
            float xs = offx + (float)(x - 1 + p % 3);
            float y0f = floorf(ys), x0f = floorf(xs);
            float wy = ys - y0f, wx = xs - x0f;
            int y0 = (int)y0f, x0 = (int)x0f;
            bool vy0 = (y0 >= 0) && (y0 < H), vy1 = (y0 + 1 >= 0) && (y0 + 1 < H);
            bool vx0 = (x0 >= 0) && (x0 < W), vx1 = (x0 + 1 >= 0) && (x0 + 1 < W);
            int yc0 = min(max(y0, 0), H - 1), yc1 = min(max(y0 + 1, 0), H - 1);
            int xc0 = min(max(x0, 0), W - 1), xc1 = min(max(x0 + 1, 0), W - 1);
            w4.x = (vy0 && vx0) ? (1.f - wy) * (1.f - wx) * m : 0.f;
            w4.y = (vy0 && vx1) ? (1.f - wy) * wx * m : 0.f;
            w4.z = (vy1 && vx0) ? wy * (1.f - wx) * m : 0.f;
            w4.w = (vy1 && vx1) ? wy * wx * m : 0.f;
            ip = (yc0 * W + xc0) | ((xc1 - xc0) << 12) | ((yc1 - yc0) << 13);
        }
        s_w4[ent] = w4;
        s_ix[ent] = ip;
    }

    int wave = t >> 6, l = t & 63;
    int l15 = l & 15, lg = l >> 4;
    int pt = wave >> 1, wo = wave & 1;           // pixel-tile, oc-half
    int cs = t & 15, pxb = t >> 4;               // gather: channel-slot / pix-base

    f32x4 acc[4];
    #pragma unroll
    for (int n = 0; n < 4; ++n) acc[n] = (f32x4){0.f, 0.f, 0.f, 0.f};

    const size_t xbase = (size_t)b * HW * CIN;

    for (int chunk = 0; chunk < 18; ++chunk) {
        __syncthreads();
        // stage B chunk (16KB) to LDS
        {
            const uint4* gsrc = (const uint4*)wb + (size_t)chunk * 1024;
            #pragma unroll
            for (int it = 0; it < 4; ++it)
                sBq[it * 256 + t] = gsrc[it * 256 + t];
        }
        // gather A chunk: 32 pix x 64 ch (of group g = chunk/9)
        {
            const ushort* xg = xbf + xbase + ((chunk < 9) ? 0 : 64) + cs * 4;
            #pragma unroll
            for (int it = 0; it < 2; ++it) {
                int pixl = pxb + it * 16;
                int ent = pixl * 18 + chunk;
                int ip = s_ix[ent];
                float4 w4 = s_w4[ent];
                int i00 = ip & 0xFFF;
                int dx = (ip >> 12) & 1, dy = (ip >> 13) & 1;
                const ushort* p00 = xg + (size_t)i00 * CIN;
                const ushort* p01 = p00 + dx * CIN;
                const ushort* p10 = p00 + dy * (W * CIN);
                const ushort* p11 = p10 + dx * CIN;
                ushort4 a00 = *(const ushort4*)p00;
                ushort4 a01 = *(const ushort4*)p01;
                ushort4 a10 = *(const ushort4*)p10;
                ushort4 a11 = *(const ushort4*)p11;
                float r0 = w4.x * bf2f(a00.x) + w4.y * bf2f(a01.x) + w4.z * bf2f(a10.x) + w4.w * bf2f(a11.x);
                float r1 = w4.x * bf2f(a00.y) + w4.y * bf2f(a01.y) + w4.z * bf2f(a10.y) + w4.w * bf2f(a11.y);
                float r2 = w4.x * bf2f(a00.z) + w4.y * bf2f(a01.z) + w4.z * bf2f(a10.z) + w4.w * bf2f(a11.z);
                float r3 = w4.x * bf2f(a00.w) + w4.y * bf2f(a01.w) + w4.z * bf2f(a10.w) + w4.w * bf2f(a11.w);
                ushort4 o4;
                o4.x = f2bf(r0); o4.y = f2bf(r1); o4.z = f2bf(r2); o4.w = f2bf(r3);
                // swizzled A write: granule u = cs>>1, u' = u ^ (pixl&7)
                *(ushort4*)(sA + pixl * 128 + (((cs >> 1)) ^ (pixl & 7)) * 16 + (cs & 1) * 8) = o4;
            }
        }
        __syncthreads();
        // MFMA: wave (pt, wo): 16 pix x 64 oc
        {
            int pixr = pt * 16 + l15;
            #pragma unroll
            for (int kh = 0; kh < 2; ++kh) {
                bf16x8 af = *(const bf16x8*)(sA + pixr * 128 + ((kh * 4 + lg) ^ (pixr & 7)) * 16);
                #pragma unroll
                for (int n = 0; n < 4; ++n) {
                    bf16x8 bfr = *(const bf16x8*)(sBq + kh * 512 + (wo * 64 + n * 16 + l15) * 4 + lg);
                    acc[n] = __builtin_amdgcn_mfma_f32_16x16x32_bf16(af, bfr, acc[n], 0, 0, 0);
                }
            }
        }
    }

    // ---- epilogue: direct NCHW float4 stores ----
    int pix0 = pt * 16 + lg * 4;
    if (w0 + pix0 < W) {
        #pragma unroll
        for (int n = 0; n < 4; ++n) {
            int o = wo * 64 + n * 16 + l15;
            float bo = bias[o];
            float4 st = {acc[n][0] + bo, acc[n][1] + bo, acc[n][2] + bo, acc[n][3] + bo};
            *(float4*)(out + ((size_t)(b * COUT + o) * H + h) * W + w0 + pix0) = st;
        }
    }
}

// ---------------- K3: per-channel BN partials, full-chip (R17 verbatim) ----------------
__global__ void k_stats1(const float* __restrict__ out, float* __restrict__ partials) {
    int bid = blockIdx.x;            // 256 = o*2 + bh
    int o = bid >> 1, bh = bid & 1;
    int t = threadIdx.x;
    const float4* op = reinterpret_cast<const float4*>(out);
    float s = 0.f, q = 0.f;
    for (int i = t; i < 4 * 784; i += 256) {
        int b = bh * 4 + i / 784, hw4 = i % 784;
        float4 v = op[(size_t)(b * COUT + o) * 784 + hw4];
        s += v.x + v.y + v.z + v.w;
        q += v.x * v.x + v.y * v.y + v.z * v.z + v.w * v.w;
    }
    __shared__ float ls[256], lq[256];
    ls[t] = s; lq[t] = q;
    __syncthreads();
    for (int st = 128; st > 0; st >>= 1) {
        if (t < st) { ls[t] += ls[t + st]; lq[t] += lq[t + st]; }
        __syncthreads();
    }
    if (t == 0) {
        partials[bid * 2]     = ls[0];
        partials[bid * 2 + 1] = lq[0];
    }
}

// ---------------- K4: BN apply (R17 verbatim) ----------------
__global__ void k_bn4(float* __restrict__ out, const float* __restrict__ partials,
                      const float* __restrict__ gamma, const float* __restrict__ beta) {
    int i = blockIdx.x * 256 + threadIdx.x;       // 802816 float4s
    int o = (i / 784) & 127;
    float s = partials[o * 4]     + partials[o * 4 + 2];
    float q = partials[o * 4 + 1] + partials[o * 4 + 3];
    const float invN = 1.f / 25088.f;
    float mean = s * invN;
    float rs = rsqrtf(q * invN - mean * mean + 1e-5f);
    float g = gamma[o] * rs;
    float bb = beta[o] - mean * g;
    float4 v = reinterpret_cast<float4*>(out)[i];
    v.x = v.x * g + bb; v.y = v.y * g + bb; v.z = v.z * g + bb; v.w = v.w * g + bb;
    reinterpret_cast<float4*>(out)[i] = v;
}

extern "C" void kernel_launch(void* const* d_in, const int* in_sizes, int n_in,
                              void* d_out, int out_size, void* d_ws, size_t ws_size,
                              hipStream_t stream) {
    const float* x     = (const float*)d_in[0];
    const float* wof   = (const float*)d_in[1];
    const float* bof   = (const float*)d_in[2];
    const float* w     = (const float*)d_in[3];
    const float* bias  = (const float*)d_in[4];
    const float* gamma = (const float*)d_in[5];
    const float* beta  = (const float*)d_in[6];
    float* out = (float*)d_out;
    float* ws  = (float*)d_ws;

    // ws layout identical to R17 (proven); partials aliases om_t head (dead there)
    float*  om_t  = ws;                           // 1354752 floats
    float*  partials = om_t;                      // 512 floats, used post-k_main2
    ushort* xbf   = (ushort*)(ws + 1355008);      // 3211264 ushorts
    ushort* wb    = xbf + 3211264;                // 147456 ushorts
    ushort* wofb  = wb + 147456;                  // 73728 ushorts

    hipLaunchKernelGGL(k_pre,     dim3(1648), dim3(256), 0, stream, x, xbf, w, wb, wof, wofb);
    hipLaunchKernelGGL(k_offc2,   dim3(896),  dim3(256), 0, stream, xbf, wofb, bof, om_t);
    hipLaunchKernelGGL(k_main2,   dim3(896),  dim3(256), 0, stream, xbf, om_t, wb, bias, out);
    hipLaunchKernelGGL(k_stats1,  dim3(256),  dim3(256), 0, stream, out, partials);
    hipLaunchKernelGGL(k_bn4,     dim3(3136), dim3(256), 0, stream, out, partials, gamma, beta);
}